// Round 1
// 552.066 us; speedup vs baseline: 1.0811x; 1.0811x over previous
//
#include <hip/hip_runtime.h>
#include <math.h>

#define DIM   4096
#define NITER 20
#define EPSF  1e-10f
#define NB    256
#define NT    1024
#define RPB   16           // rows per block
#define NRG   16           // fallback path

typedef __attribute__((ext_vector_type(4))) unsigned short ushort4_t;

// ---------- bf16 <-> f32 (bf16 chosen: range to 2^127 covers E=exp(la) spread) ---
__device__ __forceinline__ float bf2f(unsigned short b) {
    unsigned int x = ((unsigned int)b) << 16;
    return __builtin_bit_cast(float, x);
}
__device__ __forceinline__ unsigned short f2bf(float f) {
    unsigned int x = __builtin_bit_cast(unsigned int, f);
    x += 0x7fffu + ((x >> 16) & 1u);          // round-to-nearest-even
    return (unsigned short)(x >> 16);
}

// ---------- MALL-coherent scalar access (no L2 maintenance needed) ----------
__device__ __forceinline__ void st_co(float* p, float v) {
    __hip_atomic_store(p, v, __ATOMIC_RELAXED, __HIP_MEMORY_SCOPE_AGENT);
}
__device__ __forceinline__ float ld_co(const float* p) {
    return __hip_atomic_load(p, __ATOMIC_RELAXED, __HIP_MEMORY_SCOPE_AGENT);
}
// packed 64-bit variants: halve the dword-granule MALL transaction count
__device__ __forceinline__ void st_co2(float* p, float a, float b) {
    unsigned long long v =
        ((unsigned long long)__builtin_bit_cast(unsigned int, b) << 32) |
        (unsigned long long)__builtin_bit_cast(unsigned int, a);
    __hip_atomic_store((unsigned long long*)p, v, __ATOMIC_RELAXED, __HIP_MEMORY_SCOPE_AGENT);
}
__device__ __forceinline__ float2 ld_co2(const float* p) {
    unsigned long long v =
        __hip_atomic_load((const unsigned long long*)p, __ATOMIC_RELAXED, __HIP_MEMORY_SCOPE_AGENT);
    float2 r;
    r.x = __builtin_bit_cast(float, (unsigned int)(v & 0xffffffffull));
    r.y = __builtin_bit_cast(float, (unsigned int)(v >> 32));
    return r;
}

// ================= monotonic grid barrier — ALL RELAXED, no wbl2/inv ============
// bar layout (64B slots): cnt[g]@32+16g (g<8). Counters never reset; barrier
// `idx` completes when every cnt[g]==32*(idx+1). Block->XCD is round-robin (b%8).
// Lanes 0-7 poll the 8 per-XCD counters directly: removes the root->gen dependent
// atomic hops of the old 3-level tree (~2 MALL round-trips per barrier).
__device__ __forceinline__ void gridbarrier(unsigned* bar, int b, unsigned idx) {
    __syncthreads();   // drains vmcnt: all block's data stores are MALL-acked
    if (threadIdx.x < 8) {
        const unsigned tgt = 32u * (idx + 1u);
        if (threadIdx.x == 0) {
            __hip_atomic_fetch_add(bar + 32 + 16 * (b & 7), 1u,
                                   __ATOMIC_RELAXED, __HIP_MEMORY_SCOPE_AGENT);
        }
        unsigned* c = bar + 32 + 16 * threadIdx.x;
        while (__hip_atomic_load(c, __ATOMIC_RELAXED, __HIP_MEMORY_SCOPE_AGENT) < tgt)
            __builtin_amdgcn_s_sleep(1);
    }
    __syncthreads();
}

__global__ void zero_bar(unsigned* bar) {
    if (threadIdx.x < 256) bar[threadIdx.x] = 0u;
}

// ============ persistent multiplicative Sinkhorn: E=exp(la) in LDS as bf16 =======
// Row step:  u_i = 1 / sum_j E_ij * w_j         (block-local, wave<->row)
// Col step:  partial_j = sum_{i in blk} E_ij*u_i  -> global sum -> w_j = 1/sum
// Output:    out_ij = E_ij * u_i * w_j
// All sums fit fp32 with ~2^60 headroom (E in [4e-7, 1.8e7]); no max-shift needed.
__global__ __launch_bounds__(NT, 4) void sinkhorn_mult(
        const float* __restrict__ logits, const float* __restrict__ noise,
        float* __restrict__ out, float* __restrict__ cg, unsigned* __restrict__ bar) {
    __shared__ unsigned short lm[RPB][DIM];  // 128 KiB: block's 16 rows of E (bf16)
    __shared__ float          lw[DIM];       //  16 KiB: local copy of w = 1/colsum
    __shared__ float          ru[RPB];       // row reciprocals u_i

    const int t = threadIdx.x;
    const int b = blockIdx.x;
    const int wave = t >> 6, lane = t & 63;
    const int g0 = b * RPB;
    float* part = out;                  // first 4 MiB of out = partial scratch

    // ---- init: E = exp(logits) / (eps - log(noise+eps))  [= exp(logits+gumbel)] ----
#pragma unroll
    for (int r = 0; r < RPB; ++r) {
        const float4 l = *(const float4*)(logits + (size_t)(g0 + r) * DIM + 4 * t);
        const float4 u = *(const float4*)(noise  + (size_t)(g0 + r) * DIM + 4 * t);
        ushort4_t e;
        e.x = f2bf(__expf(l.x) * __builtin_amdgcn_rcpf(EPSF - __logf(u.x + EPSF)));
        e.y = f2bf(__expf(l.y) * __builtin_amdgcn_rcpf(EPSF - __logf(u.y + EPSF)));
        e.z = f2bf(__expf(l.z) * __builtin_amdgcn_rcpf(EPSF - __logf(u.z + EPSF)));
        e.w = f2bf(__expf(l.w) * __builtin_amdgcn_rcpf(EPSF - __logf(u.w + EPSF)));
        *(ushort4_t*)&lm[r][4 * t] = e;
    }
    *(float4*)&lw[4 * t] = make_float4(1.f, 1.f, 1.f, 1.f);
    __syncthreads();

    for (int it = 0; it < NITER; ++it) {
        // ---------- row sums: wave w <-> row w, single FMA pass, shfl butterfly ----
        {
            float4 s4 = make_float4(0.f, 0.f, 0.f, 0.f);
#pragma unroll
            for (int k = 0; k < 16; ++k) {
                const int col = (k * 64 + lane) * 4;
                const ushort4_t e  = *(const ushort4_t*)&lm[wave][col];
                const float4    w4 = *(const float4*)&lw[col];
                s4.x += bf2f(e.x) * w4.x;
                s4.y += bf2f(e.y) * w4.y;
                s4.z += bf2f(e.z) * w4.z;
                s4.w += bf2f(e.w) * w4.w;
            }
            float s = (s4.x + s4.y) + (s4.z + s4.w);
#pragma unroll
            for (int o = 1; o < 64; o <<= 1) s += __shfl_xor(s, o, 64);
            if (lane == 0) ru[wave] = __builtin_amdgcn_rcpf(s);
        }
        __syncthreads();

        // ---------- col partials: thread t <-> cols 4t..4t+3 over 16 rows ----
        {
            float4 p = make_float4(0.f, 0.f, 0.f, 0.f);
#pragma unroll
            for (int r2 = 0; r2 < RPB; ++r2) {
                const ushort4_t e = *(const ushort4_t*)&lm[r2][4 * t];
                const float uu = ru[r2];
                p.x += bf2f(e.x) * uu;
                p.y += bf2f(e.y) * uu;
                p.z += bf2f(e.z) * uu;
                p.w += bf2f(e.w) * uu;
            }
            float* pp = part + (size_t)b * DIM + 4 * t;
            st_co2(pp + 0, p.x, p.y);
            st_co2(pp + 2, p.z, p.w);
        }

        gridbarrier(bar, b, 2u * it);

        // ---------- combine: wave w -> colsum[16b + w] = plain sum of 256 partials --
        {
            const int jj = g0 + wave;
            float s = ld_co(part + (size_t)(lane      ) * DIM + jj)
                    + ld_co(part + (size_t)(lane +  64) * DIM + jj)
                    + ld_co(part + (size_t)(lane + 128) * DIM + jj)
                    + ld_co(part + (size_t)(lane + 192) * DIM + jj);
#pragma unroll
            for (int o = 1; o < 64; o <<= 1) s += __shfl_xor(s, o, 64);
            if (lane == 0) st_co(cg + jj, s);
        }

        gridbarrier(bar, b, 2u * it + 1u);

        // ---------- refresh local w = 1/colsum (packed 64-bit MALL reads) ----------
        {
            const float2 a = ld_co2(cg + 4 * t + 0);
            const float2 c2 = ld_co2(cg + 4 * t + 2);
            lw[4 * t + 0] = __builtin_amdgcn_rcpf(a.x);
            lw[4 * t + 1] = __builtin_amdgcn_rcpf(a.y);
            lw[4 * t + 2] = __builtin_amdgcn_rcpf(c2.x);
            lw[4 * t + 3] = __builtin_amdgcn_rcpf(c2.y);
        }
        __syncthreads();
    }

    // ---------- final: out = E * u_i * w_j ----------
    const float4 w4 = *(const float4*)&lw[4 * t];
#pragma unroll
    for (int r = 0; r < RPB; ++r) {
        const ushort4_t e = *(const ushort4_t*)&lm[r][4 * t];
        const float uu = ru[r];
        float4 o;
        o.x = bf2f(e.x) * (uu * w4.x);
        o.y = bf2f(e.y) * (uu * w4.y);
        o.z = bf2f(e.z) * (uu * w4.z);
        o.w = bf2f(e.w) * (uu * w4.w);
        *(float4*)(out + (size_t)(g0 + r) * DIM + 4 * t) = o;
    }
}

// =================== fallback pipeline (round-1, known-good 769 us) ==============
__device__ __forceinline__ float waveMaxF(float v) {
#pragma unroll
    for (int o = 32; o > 0; o >>= 1) v = fmaxf(v, __shfl_down(v, o, 64));
    return v;
}
__device__ __forceinline__ float waveSumF(float v) {
#pragma unroll
    for (int o = 32; o > 0; o >>= 1) v += __shfl_down(v, o, 64);
    return v;
}

__global__ __launch_bounds__(256) void init_k(const float* __restrict__ logits,
                                              const float* __restrict__ noise,
                                              float* __restrict__ L0,
                                              float* __restrict__ c) {
    int idx = blockIdx.x * blockDim.x + threadIdx.x;
    int stride = gridDim.x * blockDim.x;
    const float4* l4 = (const float4*)logits;
    const float4* n4 = (const float4*)noise;
    float4* o4 = (float4*)L0;
    for (int p = idx; p < DIM * DIM / 4; p += stride) {
        float4 l = l4[p];
        float4 u = n4[p];
        float4 o;
        o.x = l.x - __logf(-__logf(u.x + EPSF) + EPSF);
        o.y = l.y - __logf(-__logf(u.y + EPSF) + EPSF);
        o.z = l.z - __logf(-__logf(u.z + EPSF) + EPSF);
        o.w = l.w - __logf(-__logf(u.w + EPSF) + EPSF);
        o4[p] = o;
    }
    if (idx < DIM) c[idx] = 0.0f;
}

__global__ __launch_bounds__(256) void row_lse(const float* __restrict__ L0,
                                               const float* __restrict__ c,
                                               float* __restrict__ r) {
    __shared__ float red[8];
    const int row = blockIdx.x;
    const int t = threadIdx.x;
    const float4* a4 = (const float4*)(L0 + (size_t)row * DIM);
    const float4* c4 = (const float4*)c;
    float v[16];
    float m = -INFINITY;
#pragma unroll
    for (int k = 0; k < 4; ++k) {
        float4 a  = a4[t + k * 256];
        float4 cc = c4[t + k * 256];
        v[4 * k + 0] = a.x - cc.x;
        v[4 * k + 1] = a.y - cc.y;
        v[4 * k + 2] = a.z - cc.z;
        v[4 * k + 3] = a.w - cc.w;
        m = fmaxf(m, fmaxf(fmaxf(v[4 * k], v[4 * k + 1]), fmaxf(v[4 * k + 2], v[4 * k + 3])));
    }
    m = waveMaxF(m);
    const int lane = t & 63, wid = t >> 6;
    if (lane == 0) red[wid] = m;
    __syncthreads();
    const float bm = fmaxf(fmaxf(red[0], red[1]), fmaxf(red[2], red[3]));
    float s = 0.0f;
#pragma unroll
    for (int q = 0; q < 16; ++q) s += __expf(v[q] - bm);
    s = waveSumF(s);
    if (lane == 0) red[4 + wid] = s;
    __syncthreads();
    if (t == 0) r[row] = bm + __logf(red[4] + red[5] + red[6] + red[7]);
}

__global__ __launch_bounds__(1024) void col_partial(const float* __restrict__ L0,
                                                    const float* __restrict__ r,
                                                    float2* __restrict__ part) {
    __shared__ float sr[256];
    __shared__ float smm[1024];
    __shared__ float sms[1024];
    const int g = blockIdx.x, h = blockIdx.y;
    const int tc = threadIdx.x & 255;
    const int ln = threadIdx.x >> 8;
    if (threadIdx.x < 256) sr[threadIdx.x] = r[h * 256 + threadIdx.x];
    __syncthreads();
    const int j = g * 256 + tc;
    float m = -INFINITY, s = 0.0f;
#pragma unroll 4
    for (int k = 0; k < 64; ++k) {
        int ii = k * 4 + ln;
        float v = L0[(size_t)(h * 256 + ii) * DIM + j] - sr[ii];
        float nm = fmaxf(m, v);
        s = s * __expf(m - nm) + __expf(v - nm);
        m = nm;
    }
    smm[threadIdx.x] = m;
    sms[threadIdx.x] = s;
    __syncthreads();
    if (threadIdx.x < 256) {
        float m0 = smm[tc], m1 = smm[tc + 256], m2 = smm[tc + 512], m3 = smm[tc + 768];
        float M = fmaxf(fmaxf(m0, m1), fmaxf(m2, m3));
        float S = sms[tc] * __expf(m0 - M) + sms[tc + 256] * __expf(m1 - M) +
                  sms[tc + 512] * __expf(m2 - M) + sms[tc + 768] * __expf(m3 - M);
        part[h * DIM + j] = make_float2(M, S);
    }
}

__global__ __launch_bounds__(256) void col_combine(const float2* __restrict__ part,
                                                   float* __restrict__ c) {
    int j = blockIdx.x * 256 + threadIdx.x;
    float pm[NRG], ps[NRG];
    float M = -INFINITY;
#pragma unroll
    for (int h = 0; h < NRG; ++h) {
        float2 p = part[h * DIM + j];
        pm[h] = p.x; ps[h] = p.y;
        M = fmaxf(M, p.x);
    }
    float S = 0.0f;
#pragma unroll
    for (int h = 0; h < NRG; ++h) S += ps[h] * __expf(pm[h] - M);
    c[j] = M + __logf(S);
}

__global__ __launch_bounds__(256) void final_exp(float* __restrict__ L0,
                                                 const float* __restrict__ r,
                                                 const float* __restrict__ c) {
    const float4* c4 = (const float4*)c;
    float4* a4 = (float4*)L0;
    int idx = blockIdx.x * blockDim.x + threadIdx.x;
    int stride = gridDim.x * blockDim.x;
    for (int p = idx; p < DIM * DIM / 4; p += stride) {
        int i  = p >> 10;
        int j4 = p & 1023;
        float4 a = a4[p];
        float rrv = r[i];
        float4 ccv = c4[j4];
        a.x = __expf(a.x - rrv - ccv.x);
        a.y = __expf(a.y - rrv - ccv.y);
        a.z = __expf(a.z - rrv - ccv.z);
        a.w = __expf(a.w - rrv - ccv.w);
        a4[p] = a;
    }
}

// ====================================== launch ===================================
extern "C" void kernel_launch(void* const* d_in, const int* in_sizes, int n_in,
                              void* d_out, int out_size, void* d_ws, size_t ws_size,
                              hipStream_t stream) {
    const float* logits = (const float*)d_in[0];
    const float* noise  = (const float*)d_in[1];
    float* out = (float*)d_out;
    float* cg  = (float*)d_ws;                          // 16 KiB global colsum
    unsigned* bar = (unsigned*)((char*)d_ws + 16384);   // barrier state

    zero_bar<<<1, 256, 0, stream>>>(bar);
    void* args[] = { (void*)&logits, (void*)&noise, (void*)&out, (void*)&cg, (void*)&bar };
    hipError_t err = hipLaunchCooperativeKernel((const void*)sinkhorn_mult,
                                                dim3(NB), dim3(NT), args, 0, stream);
    if (err != hipSuccess) {
        // fallback: round-1 multi-kernel pipeline (known-good)
        float* ws = (float*)d_ws;
        float*  r    = ws;
        float*  cf   = ws + DIM;
        float2* part = (float2*)(ws + 2 * DIM);
        init_k<<<4096, 256, 0, stream>>>(logits, noise, out, cf);
        for (int t = 0; t < NITER; ++t) {
            row_lse<<<DIM, 256, 0, stream>>>(out, cf, r);
            col_partial<<<dim3(16, 16), 1024, 0, stream>>>(out, r, part);
            col_combine<<<16, 256, 0, stream>>>(part, cf);
        }
        final_exp<<<4096, 256, 0, stream>>>(out, r, cf);
    }
}